// Round 3
// baseline (1165.642 us; speedup 1.0000x reference)
//
#include <hip/hip_runtime.h>

#define NLAT 721
#define NLON 1440
#define NB 4
#define ND 5
#define NROWS (NLAT*ND)          // 3605
#define PLANE (NLAT*NLON)        // 1,038,240
#define HVOL (NB*PLANE)          // 4,152,960
#define DTSTEP 0.01f
#define TAPCAP 262144
#define TCH 256                  // taps per chunk (multiple of 4)

// ---- heavy kernel geometry (polar lats: l<16 or l>=705) ----
#define HLAT 16                  // heavy lats per side
#define NHEAVY (2*HLAT)          // 32 heavy lats
#define NCH 240                  // lon columns per heavy block (6 per row)
#define NT 4                     // tap-teams per block
#define TBT 192                  // threads per team (3 waves)
#define BT (NT*TBT)              // 768 block threads
#define ACTH 60                  // compute threads per team (x4 cols = 240)
#define SH_SZH (NCH + TCH + 8)   // 504 floats per staging array
#define TEAM_F (3*SH_SZH + 4*TCH) // 2536 floats per team slice (10144 B)

// ---- light kernel geometry (lats 16..704) ----
#define NLIGHT (NLAT - NHEAVY)   // 689
#define LBT 384                  // block threads (6 waves)
#define LACT 360                 // active (x4 cols = 1440)

// ---------------------------------------------------------------------------
// Kernel A: per (lat,d) row, find the wrapped-interval support [jlo, jhi]
// ---------------------------------------------------------------------------
__global__ __launch_bounds__(64) void support_kernel(
    const float* __restrict__ Kgc, const float* __restrict__ Kgs,
    const float* __restrict__ Kdc, const float* __restrict__ Kds,
    int* __restrict__ jlo_a, int* __restrict__ cnt_a)
{
  int row = blockIdx.x;
  int lane = threadIdx.x;
  const float* a = Kgc + (size_t)row * NLON;
  const float* b = Kgs + (size_t)row * NLON;
  const float* c = Kdc + (size_t)row * NLON;
  const float* d = Kds + (size_t)row * NLON;
  int jmin = 1 << 30, jmax = -(1 << 30);
  for (int m = lane; m < NLON; m += 64) {
    float s = fabsf(a[m]) + fabsf(b[m]) + fabsf(c[m]) + fabsf(d[m]);
    if (s != 0.0f) {
      int j = (m >= NLON / 2) ? (m - NLON) : m;
      jmin = min(jmin, j);
      jmax = max(jmax, j);
    }
  }
  for (int s = 32; s > 0; s >>= 1) {
    jmin = min(jmin, __shfl_down(jmin, s));
    jmax = max(jmax, __shfl_down(jmax, s));
  }
  if (lane == 0) {
    if (jmax < jmin) { jlo_a[row] = 0; cnt_a[row] = 0; }
    else             { jlo_a[row] = jmin; cnt_a[row] = jmax - jmin + 1; }
  }
}

// ---------------------------------------------------------------------------
// Kernel B: prefix sum over 4-padded row counts; per-row meta
// int4(iq*NLON, jlo (signed), cnt4, pool offset).
// ---------------------------------------------------------------------------
__global__ __launch_bounds__(256) void scan_kernel(
    const int* __restrict__ cnt_a, const int* __restrict__ jlo_a,
    int* __restrict__ off_a, int4* __restrict__ rowmeta, int tap_cap)
{
  __shared__ int buf[256];
  __shared__ int carry;
  int tid = threadIdx.x;
  if (tid == 0) carry = 0;
  __syncthreads();
  for (int base = 0; base < NROWS; base += 256) {
    int i = base + tid;
    int v = (i < NROWS) ? ((cnt_a[i] + 3) & ~3) : 0;
    buf[tid] = v;
    __syncthreads();
    for (int s = 1; s < 256; s <<= 1) {
      int t = (tid >= s) ? buf[tid - s] : 0;
      __syncthreads();
      buf[tid] += t;
      __syncthreads();
    }
    if (i < NROWS) off_a[i] = carry + buf[tid] - v;   // exclusive
    __syncthreads();
    if (tid == 255) carry += buf[255];
    __syncthreads();
  }
  __syncthreads();
  for (int r = tid; r < NROWS; r += 256) {
    int off = off_a[r];
    int c4  = (cnt_a[r] + 3) & ~3;
    if (off >= tap_cap)           c4 = 0;
    else if (off + c4 > tap_cap)  c4 = (tap_cap - off) & ~3;
    int l = r / ND, d = r - ND * l;
    int iq = min(max(l + d - 2, 0), NLAT - 1);
    rowmeta[r] = make_int4(iq * NLON, jlo_a[r], c4, off);
  }
}

// ---------------------------------------------------------------------------
// Kernel C: fill weight pool (Kg_c, Kg_s, Kd_c, Kd_s), zero-padded to x4.
// ---------------------------------------------------------------------------
__global__ __launch_bounds__(64) void fill_kernel(
    const float* __restrict__ Kgc, const float* __restrict__ Kgs,
    const float* __restrict__ Kdc, const float* __restrict__ Kds,
    const int* __restrict__ jlo_a, const int* __restrict__ cnt_a,
    const int* __restrict__ off_a,
    float4* __restrict__ tapw, int tap_cap)
{
  int row = blockIdx.x;
  int jlo = jlo_a[row], cnt = cnt_a[row], off = off_a[row];
  int cnt4 = (cnt + 3) & ~3;
  for (int t = threadIdx.x; t < cnt4; t += 64) {
    int p = off + t;
    if (p >= tap_cap) break;
    float4 w = make_float4(0.f, 0.f, 0.f, 0.f);
    if (t < cnt) {
      int j = jlo + t;
      int m = j + ((j < 0) ? NLON : 0);
      size_t idx = (size_t)row * NLON + m;
      w = make_float4(Kgc[idx], Kgs[idx], Kdc[idx], Kds[idx]);
    }
    tapw[p] = w;
  }
}

// ---------------------------------------------------------------------------
// Shared epilogue: Coriolis + RK4 combine for 4 consecutive columns at ih.
// mode 0: O = S0 + cdt*k ; mode 1: O = (X1+2*X2+X3-S0)/3 + (DT/6)*k4
// ---------------------------------------------------------------------------
__device__ __forceinline__ void rk4_epilogue(
    float ah0, float ah1, float ah2, float ah3,
    float au0, float au1, float au2, float au3,
    float av0, float av1, float av2, float av3,
    size_t ih, float f,
    const float* __restrict__ Xh,  const float* __restrict__ Xuv,
    const float* __restrict__ S0h, const float* __restrict__ S0uv,
    const float* __restrict__ X1h, const float* __restrict__ X1uv,
    const float* __restrict__ X2h, const float* __restrict__ X2uv,
    float* __restrict__ Oh, float* __restrict__ Ouv,
    float cdt, int mode)
{
  size_t iuv = 2 * ih;
  float4 xa = *(const float4*)(Xuv + iuv);      // u0,v0,u1,v1
  float4 xb = *(const float4*)(Xuv + iuv + 4);  // u2,v2,u3,v3
  float kh0 = -ah0, kh1 = -ah1, kh2 = -ah2, kh3 = -ah3;
  float ku0 = fmaf(-f, xa.y, -au0), kv0 = fmaf(f, xa.x, -av0);
  float ku1 = fmaf(-f, xa.w, -au1), kv1 = fmaf(f, xa.z, -av1);
  float ku2 = fmaf(-f, xb.y, -au2), kv2 = fmaf(f, xb.x, -av2);
  float ku3 = fmaf(-f, xb.w, -au3), kv3 = fmaf(f, xb.z, -av3);

  if (mode == 0) {
    float4 s0 = *(const float4*)(S0h + ih);
    *(float4*)(Oh + ih) = make_float4(fmaf(cdt, kh0, s0.x), fmaf(cdt, kh1, s0.y),
                                      fmaf(cdt, kh2, s0.z), fmaf(cdt, kh3, s0.w));
    float4 sa = *(const float4*)(S0uv + iuv);
    float4 sb = *(const float4*)(S0uv + iuv + 4);
    *(float4*)(Ouv + iuv)     = make_float4(fmaf(cdt, ku0, sa.x), fmaf(cdt, kv0, sa.y),
                                            fmaf(cdt, ku1, sa.z), fmaf(cdt, kv1, sa.w));
    *(float4*)(Ouv + iuv + 4) = make_float4(fmaf(cdt, ku2, sb.x), fmaf(cdt, kv2, sb.y),
                                            fmaf(cdt, ku3, sb.z), fmaf(cdt, kv3, sb.w));
  } else {
    const float DT6 = DTSTEP / 6.0f;
    const float TH  = 1.0f / 3.0f;
    float4 xh3 = *(const float4*)(Xh + ih);   // X3 h at own cols
    float4 s0 = *(const float4*)(S0h + ih);
    float4 x1 = *(const float4*)(X1h + ih);
    float4 x2 = *(const float4*)(X2h + ih);
    *(float4*)(Oh + ih) = make_float4(
      TH * (x1.x + 2.f * x2.x + xh3.x - s0.x) + DT6 * kh0,
      TH * (x1.y + 2.f * x2.y + xh3.y - s0.y) + DT6 * kh1,
      TH * (x1.z + 2.f * x2.z + xh3.z - s0.z) + DT6 * kh2,
      TH * (x1.w + 2.f * x2.w + xh3.w - s0.w) + DT6 * kh3);
    float4 sa = *(const float4*)(S0uv + iuv);
    float4 sb = *(const float4*)(S0uv + iuv + 4);
    float4 xa1 = *(const float4*)(X1uv + iuv);
    float4 xb1 = *(const float4*)(X1uv + iuv + 4);
    float4 xa2 = *(const float4*)(X2uv + iuv);
    float4 xb2 = *(const float4*)(X2uv + iuv + 4);
    *(float4*)(Ouv + iuv) = make_float4(
      TH * (xa1.x + 2.f * xa2.x + xa.x - sa.x) + DT6 * ku0,
      TH * (xa1.y + 2.f * xa2.y + xa.y - sa.y) + DT6 * kv0,
      TH * (xa1.z + 2.f * xa2.z + xa.z - sa.z) + DT6 * ku1,
      TH * (xa1.w + 2.f * xa2.w + xa.w - sa.w) + DT6 * kv1);
    *(float4*)(Ouv + iuv + 4) = make_float4(
      TH * (xb1.x + 2.f * xb2.x + xb.x - sb.x) + DT6 * ku2,
      TH * (xb1.y + 2.f * xb2.y + xb.y - sb.y) + DT6 * kv2,
      TH * (xb1.z + 2.f * xb2.z + xb.z - sb.z) + DT6 * ku3,
      TH * (xb1.w + 2.f * xb2.w + xb.w - sb.w) + DT6 * kv3);
  }
}

// 16 FMAs for one tap (weights W), elements a..d per column 0..3
#define TAP(W, a, b, c, d)                                                   \
  ah0 = fmaf(W.z, U##a, ah0); ah0 = fmaf(W.w, V##a, ah0);                    \
  au0 = fmaf(W.x, H##a, au0); av0 = fmaf(W.y, H##a, av0);                    \
  ah1 = fmaf(W.z, U##b, ah1); ah1 = fmaf(W.w, V##b, ah1);                    \
  au1 = fmaf(W.x, H##b, au1); av1 = fmaf(W.y, H##b, av1);                    \
  ah2 = fmaf(W.z, U##c, ah2); ah2 = fmaf(W.w, V##c, ah2);                    \
  au2 = fmaf(W.x, H##c, au2); av2 = fmaf(W.y, H##c, av2);                    \
  ah3 = fmaf(W.z, U##d, ah3); ah3 = fmaf(W.w, V##d, ah3);                    \
  au3 = fmaf(W.x, H##d, au3); av3 = fmaf(W.y, H##d, av3);

// ---------------------------------------------------------------------------
// HEAVY kernel (polar lats).  Grid 768 = 32 lats x 4 batch x 6 col-blocks.
// Block 768 = 4 tap-teams x 192 threads; each team stages its own LDS slice
// for its 256-tap chunk over 240 columns; lockstep items across teams; final
// LDS combine by team 0.  Column-split 6x spreads one polar lat over 24 CUs.
// ---------------------------------------------------------------------------
__global__ __launch_bounds__(BT, 4) void heavy_kernel(
    const float* __restrict__ Xh,  const float* __restrict__ Xuv,
    const float* __restrict__ S0h, const float* __restrict__ S0uv,
    const float* __restrict__ X1h, const float* __restrict__ X1uv,
    const float* __restrict__ X2h, const float* __restrict__ X2uv,
    const float* __restrict__ fcor,
    const int4* __restrict__ rowmeta, const float4* __restrict__ tapw,
    float* __restrict__ Oh, float* __restrict__ Ouv,
    float cdt, int mode)
{
  __shared__ __align__(16) float smem[NT * TEAM_F];

  int id = blockIdx.x;
  int hi = id % NHEAVY;
  int r  = id / NHEAVY;
  int b  = r & 3;
  int cb = r >> 2;                   // 0..5
  int l  = (hi & 1) ? (NLAT - 1 - (hi >> 1)) : (hi >> 1);
  int c0 = cb * NCH;
  int tid  = threadIdx.x;
  int team = tid / TBT;              // 0..NT-1
  int ttid = tid - team * TBT;       // 0..TBT-1
  bool act = ttid < ACTH;
  int w = 4 * ttid;                  // local col base (act threads)

  float* __restrict__ sl = smem + team * TEAM_F;
  float* __restrict__ sh = sl;
  float* __restrict__ su = sl + SH_SZH;
  float* __restrict__ sv = sl + 2 * SH_SZH;
  float4* __restrict__ swt = (float4*)(sl + 3 * SH_SZH);

  const float* __restrict__ xh  = Xh  + (size_t)b * PLANE;
  const float* __restrict__ xuv = Xuv + (size_t)b * PLANE * 2;

  // --- uniform per-lat work-item partition: item -> (d row, tap chunk) ---
  int4 rms[ND];
  int ns[ND + 1];
  ns[0] = 0;
#pragma unroll
  for (int d = 0; d < ND; ++d) {
    rms[d] = rowmeta[l * ND + d];
    ns[d + 1] = ns[d] + (rms[d].z + TCH - 1) / TCH;
  }
  int nit = ns[ND];

  float ah0 = 0.f, ah1 = 0.f, ah2 = 0.f, ah3 = 0.f;
  float au0 = 0.f, au1 = 0.f, au2 = 0.f, au3 = 0.f;
  float av0 = 0.f, av1 = 0.f, av2 = 0.f, av3 = 0.f;

  for (int it0 = 0; it0 < nit; it0 += NT) {
    int item = it0 + team;
    int tc = -1;
    int4 rm = make_int4(0, 0, 0, 0);
#pragma unroll
    for (int d = 0; d < ND; ++d)
      if (item >= ns[d] && item < ns[d + 1]) { rm = rms[d]; tc = (item - ns[d]) * TCH; }

    __syncthreads();                        // prior iteration's readers done
    int wcnt = 0;
    if (tc >= 0) {
      wcnt = min(TCH, rm.z - tc);           // multiple of 4
      int wlen = NCH - 1 + wcnt + 3;        // indices 0 .. 242+wcnt
      int gg = c0 + rm.y + tc;              // window start, unwrapped
      gg %= NLON; gg += (gg < 0) ? NLON : 0;
      const float* __restrict__ grh  = xh  + rm.x;
      const float* __restrict__ gruv = xuv + 2 * (size_t)rm.x;
      for (int e = ttid; e < wlen; e += TBT) {
        int g = gg + e;                     // < 1440 + 504
        g -= (g >= NLON) ? NLON : 0;
        float  hh = grh[g];
        float2 uv = *(const float2*)(gruv + 2 * g);
        sh[e] = hh; su[e] = uv.x; sv[e] = uv.y;
      }
      for (int k = ttid; k < wcnt; k += TBT) swt[k] = tapw[rm.w + tc + k];
    }
    __syncthreads();                        // all teams staged

    if (tc >= 0 && act) {
      const float4* __restrict__ ph = (const float4*)(sh + w);  // 16B aligned
      const float4* __restrict__ pu = (const float4*)(su + w);
      const float4* __restrict__ pv = (const float4*)(sv + w);
      float4 Ha = ph[0], Ua = pu[0], Va = pv[0];
      for (int tg = 0; tg < wcnt; tg += 4) {
        int q = (tg >> 2) + 1;
        float4 W0 = swt[tg], W1 = swt[tg + 1], W2 = swt[tg + 2], W3 = swt[tg + 3];
        float4 Hb = ph[q], Ub = pu[q], Vb = pv[q];
        float H0 = Ha.x, H1 = Ha.y, H2 = Ha.z, H3 = Ha.w;
        float H4 = Hb.x, H5 = Hb.y, H6 = Hb.z;
        float U0 = Ua.x, U1 = Ua.y, U2 = Ua.z, U3 = Ua.w;
        float U4 = Ub.x, U5 = Ub.y, U6 = Ub.z;
        float V0 = Va.x, V1 = Va.y, V2 = Va.z, V3 = Va.w;
        float V4 = Vb.x, V5 = Vb.y, V6 = Vb.z;
        TAP(W0, 0, 1, 2, 3)
        TAP(W1, 1, 2, 3, 4)
        TAP(W2, 2, 3, 4, 5)
        TAP(W3, 3, 4, 5, 6)
        Ha = Hb; Ua = Ub; Va = Vb;
      }
    }
  }

  // ---- cross-team combine: teams 1..3 dump partials into own slice ----
  __syncthreads();                          // all compute reads of LDS done
  if (team != 0 && act) {
    *(float4*)(sh + w) = make_float4(ah0, ah1, ah2, ah3);
    *(float4*)(su + w) = make_float4(au0, au1, au2, au3);
    *(float4*)(sv + w) = make_float4(av0, av1, av2, av3);
  }
  __syncthreads();

  if (team == 0 && act) {
#pragma unroll
    for (int t = 1; t < NT; ++t) {
      const float* __restrict__ s2 = smem + t * TEAM_F;
      float4 A = *(const float4*)(s2 + w);
      float4 B = *(const float4*)(s2 + SH_SZH + w);
      float4 C = *(const float4*)(s2 + 2 * SH_SZH + w);
      ah0 += A.x; ah1 += A.y; ah2 += A.z; ah3 += A.w;
      au0 += B.x; au1 += B.y; au2 += B.z; au3 += B.w;
      av0 += C.x; av1 += C.y; av2 += C.z; av3 += C.w;
    }
    size_t ih = (size_t)b * PLANE + (size_t)l * NLON + c0 + w;
    rk4_epilogue(ah0, ah1, ah2, ah3, au0, au1, au2, au3, av0, av1, av2, av3,
                 ih, fcor[l], Xh, Xuv, S0h, S0uv, X1h, X1uv, X2h, X2uv,
                 Oh, Ouv, cdt, mode);
  }
}

// ---------------------------------------------------------------------------
// LIGHT kernel (lats 16..704).  Grid 689*4, block 384 (360 active).
// Thread owns 4 contiguous columns of one (lat,batch) row; rolling 4-elem
// register window read directly from global (L1/L2/L3-resident rows); taps
// from tapw pool (uniform broadcast).  No LDS, no barriers.
// ---------------------------------------------------------------------------
__global__ __launch_bounds__(LBT) void light_kernel(
    const float* __restrict__ Xh,  const float* __restrict__ Xuv,
    const float* __restrict__ S0h, const float* __restrict__ S0uv,
    const float* __restrict__ X1h, const float* __restrict__ X1uv,
    const float* __restrict__ X2h, const float* __restrict__ X2uv,
    const float* __restrict__ fcor,
    const int4* __restrict__ rowmeta, const float4* __restrict__ tapw,
    float* __restrict__ Oh, float* __restrict__ Ouv,
    float cdt, int mode)
{
  int id = blockIdx.x;
  int li = id % NLIGHT;
  int b  = id / NLIGHT;
  int l  = HLAT + li;                // 16 .. 704
  int tid = threadIdx.x;
  if (tid >= LACT) return;
  int w4 = 4 * tid;                  // col base, 0..1436

  const float* __restrict__ xh  = Xh  + (size_t)b * PLANE;
  const float* __restrict__ xuv = Xuv + (size_t)b * PLANE * 2;

  float ah0 = 0.f, ah1 = 0.f, ah2 = 0.f, ah3 = 0.f;
  float au0 = 0.f, au1 = 0.f, au2 = 0.f, au3 = 0.f;
  float av0 = 0.f, av1 = 0.f, av2 = 0.f, av3 = 0.f;

  for (int d = 0; d < ND; ++d) {
    int4 rm = rowmeta[l * ND + d];   // (iq*NLON, jlo, cnt4, off) — uniform
    int cnt = rm.z;
    if (cnt == 0) continue;
    const float* __restrict__ grh  = xh  + rm.x;
    const float* __restrict__ gruv = xuv + 2 * (size_t)rm.x;

    int p0 = w4 + rm.y;              // element position of col0 at tap 0
    // initial 4-element window (individually wrapped)
    int g0 = p0;     g0 += (g0 < 0) ? NLON : 0; g0 -= (g0 >= NLON) ? NLON : 0;
    int g1 = p0 + 1; g1 += (g1 < 0) ? NLON : 0; g1 -= (g1 >= NLON) ? NLON : 0;
    int g2 = p0 + 2; g2 += (g2 < 0) ? NLON : 0; g2 -= (g2 >= NLON) ? NLON : 0;
    int g3 = p0 + 3; g3 += (g3 < 0) ? NLON : 0; g3 -= (g3 >= NLON) ? NLON : 0;
    float H0 = grh[g0], H1 = grh[g1], H2 = grh[g2], H3 = grh[g3];
    float2 t0 = *(const float2*)(gruv + 2 * g0);
    float2 t1 = *(const float2*)(gruv + 2 * g1);
    float2 t2 = *(const float2*)(gruv + 2 * g2);
    float2 t3 = *(const float2*)(gruv + 2 * g3);
    float U0 = t0.x, U1 = t1.x, U2 = t2.x, U3 = t3.x;
    float V0 = t0.y, V1 = t1.y, V2 = t2.y, V3 = t3.y;

    const float4* __restrict__ wp = tapw + rm.w;
#pragma unroll 4
    for (int t = 0; t < cnt; ++t) {
      float4 W = wp[t];
      int gn = p0 + t + 4;           // next element (prefetch; in [-716, 2163])
      gn += (gn < 0) ? NLON : 0; gn -= (gn >= NLON) ? NLON : 0;
      float  hn = grh[gn];
      float2 un = *(const float2*)(gruv + 2 * gn);
      ah0 = fmaf(W.z, U0, ah0); ah0 = fmaf(W.w, V0, ah0);
      au0 = fmaf(W.x, H0, au0); av0 = fmaf(W.y, H0, av0);
      ah1 = fmaf(W.z, U1, ah1); ah1 = fmaf(W.w, V1, ah1);
      au1 = fmaf(W.x, H1, au1); av1 = fmaf(W.y, H1, av1);
      ah2 = fmaf(W.z, U2, ah2); ah2 = fmaf(W.w, V2, ah2);
      au2 = fmaf(W.x, H2, au2); av2 = fmaf(W.y, H2, av2);
      ah3 = fmaf(W.z, U3, ah3); ah3 = fmaf(W.w, V3, ah3);
      au3 = fmaf(W.x, H3, au3); av3 = fmaf(W.y, H3, av3);
      H0 = H1; H1 = H2; H2 = H3; H3 = hn;
      U0 = U1; U1 = U2; U2 = U3; U3 = un.x;
      V0 = V1; V1 = V2; V2 = V3; V3 = un.y;
    }
  }

  size_t ih = (size_t)b * PLANE + (size_t)l * NLON + w4;
  rk4_epilogue(ah0, ah1, ah2, ah3, au0, au1, au2, au3, av0, av1, av2, av3,
               ih, fcor[l], Xh, Xuv, S0h, S0uv, X1h, X1uv, X2h, X2uv,
               Oh, Ouv, cdt, mode);
}

// ---------------------------------------------------------------------------
extern "C" void kernel_launch(void* const* d_in, const int* in_sizes, int n_in,
                              void* d_out, int out_size, void* d_ws, size_t ws_size,
                              hipStream_t stream)
{
  const float* h0   = (const float*)d_in[0];
  const float* uv0  = (const float*)d_in[1];
  const float* Kgc  = (const float*)d_in[2];
  const float* Kgs  = (const float*)d_in[3];
  const float* Kdc  = (const float*)d_in[4];
  const float* Kds  = (const float*)d_in[5];
  const float* fcor = (const float*)d_in[6];

  char* ws = (char*)d_ws;
  size_t pos = 0;
  auto carve = [&](size_t bytes) -> void* {
    void* p = ws + pos;
    pos += (bytes + 255) & ~(size_t)255;
    return p;
  };

  int*   jlo_a   = (int*)carve(sizeof(int) * NROWS);
  int*   cnt_a   = (int*)carve(sizeof(int) * NROWS);
  int*   off_a   = (int*)carve(sizeof(int) * NROWS);
  int4*  rowmeta = (int4*)carve(sizeof(int4) * NROWS);
  float* X1      = (float*)carve(sizeof(float) * 3 * (size_t)HVOL);
  float* X2      = (float*)carve(sizeof(float) * 3 * (size_t)HVOL);
  float* X3      = (float*)carve(sizeof(float) * 3 * (size_t)HVOL);
  float4* tapw   = (float4*)carve(sizeof(float4) * (size_t)TAPCAP);

  float* X1h = X1;  float* X1uv = X1 + HVOL;
  float* X2h = X2;  float* X2uv = X2 + HVOL;
  float* X3h = X3;  float* X3uv = X3 + HVOL;
  float* out_h  = (float*)d_out;          // [NB,1,NLAT,NLON]
  float* out_uv = (float*)d_out + HVOL;   // [NB,1,NLAT,NLON,2]

  support_kernel<<<NROWS, 64, 0, stream>>>(Kgc, Kgs, Kdc, Kds, jlo_a, cnt_a);
  scan_kernel<<<1, 256, 0, stream>>>(cnt_a, jlo_a, off_a, rowmeta, TAPCAP);
  fill_kernel<<<NROWS, 64, 0, stream>>>(Kgc, Kgs, Kdc, Kds, jlo_a, cnt_a, off_a,
                                        tapw, TAPCAP);

  dim3 gh(NHEAVY * NB * 6);
  dim3 gl(NLIGHT * NB);

  // stage 1: k1 from S0; X1 = S0 + dt/2 k1
  heavy_kernel<<<gh, BT, 0, stream>>>(h0, uv0, h0, uv0, h0, uv0, h0, uv0, fcor,
                                      rowmeta, tapw, X1h, X1uv, 0.5f * DTSTEP, 0);
  light_kernel<<<gl, LBT, 0, stream>>>(h0, uv0, h0, uv0, h0, uv0, h0, uv0, fcor,
                                       rowmeta, tapw, X1h, X1uv, 0.5f * DTSTEP, 0);
  // stage 2: k2 from X1; X2 = S0 + dt/2 k2
  heavy_kernel<<<gh, BT, 0, stream>>>(X1h, X1uv, h0, uv0, h0, uv0, h0, uv0, fcor,
                                      rowmeta, tapw, X2h, X2uv, 0.5f * DTSTEP, 0);
  light_kernel<<<gl, LBT, 0, stream>>>(X1h, X1uv, h0, uv0, h0, uv0, h0, uv0, fcor,
                                       rowmeta, tapw, X2h, X2uv, 0.5f * DTSTEP, 0);
  // stage 3: k3 from X2; X3 = S0 + dt k3
  heavy_kernel<<<gh, BT, 0, stream>>>(X2h, X2uv, h0, uv0, h0, uv0, h0, uv0, fcor,
                                      rowmeta, tapw, X3h, X3uv, DTSTEP, 0);
  light_kernel<<<gl, LBT, 0, stream>>>(X2h, X2uv, h0, uv0, h0, uv0, h0, uv0, fcor,
                                       rowmeta, tapw, X3h, X3uv, DTSTEP, 0);
  // stage 4: k4 from X3; out = (X1 + 2 X2 + X3 - S0)/3 + dt/6 k4
  heavy_kernel<<<gh, BT, 0, stream>>>(X3h, X3uv, h0, uv0, X1h, X1uv, X2h, X2uv, fcor,
                                      rowmeta, tapw, out_h, out_uv, 0.0f, 1);
  light_kernel<<<gl, LBT, 0, stream>>>(X3h, X3uv, h0, uv0, X1h, X1uv, X2h, X2uv, fcor,
                                       rowmeta, tapw, out_h, out_uv, 0.0f, 1);
}

// Round 4
// 1063.498 us; speedup vs baseline: 1.0960x; 1.0960x over previous
//
#include <hip/hip_runtime.h>

#define NLAT 721
#define NLON 1440
#define NB 4
#define ND 5
#define NROWS (NLAT*ND)          // 3605
#define PLANE (NLAT*NLON)        // 1,038,240
#define HVOL (NB*PLANE)          // 4,152,960
#define DTSTEP 0.01f
#define TAPCAP 262144

// ---- stage kernel geometry ----
#define NCK 512                  // cols per block (lane owns 8)
#define TCHK 64                  // taps per team-chunk (multiple of 4)
#define NTK 8                    // wave-teams per block
#define BTK (NTK*64)             // 512 threads
#define WLK 608                  // per-field slice floats (512+64+4 + swizzle pad)
#define TFK (3*WLK)              // team slice floats (1824 -> 7296 B; x8 = 58 KB)

// ---------------------------------------------------------------------------
// Kernel A: per (lat,d) row, find the wrapped-interval support [jlo, jhi]
// ---------------------------------------------------------------------------
__global__ __launch_bounds__(64) void support_kernel(
    const float* __restrict__ Kgc, const float* __restrict__ Kgs,
    const float* __restrict__ Kdc, const float* __restrict__ Kds,
    int* __restrict__ jlo_a, int* __restrict__ cnt_a)
{
  int row = blockIdx.x;
  int lane = threadIdx.x;
  const float* a = Kgc + (size_t)row * NLON;
  const float* b = Kgs + (size_t)row * NLON;
  const float* c = Kdc + (size_t)row * NLON;
  const float* d = Kds + (size_t)row * NLON;
  int jmin = 1 << 30, jmax = -(1 << 30);
  for (int m = lane; m < NLON; m += 64) {
    float s = fabsf(a[m]) + fabsf(b[m]) + fabsf(c[m]) + fabsf(d[m]);
    if (s != 0.0f) {
      int j = (m >= NLON / 2) ? (m - NLON) : m;
      jmin = min(jmin, j);
      jmax = max(jmax, j);
    }
  }
  for (int s = 32; s > 0; s >>= 1) {
    jmin = min(jmin, __shfl_down(jmin, s));
    jmax = max(jmax, __shfl_down(jmax, s));
  }
  if (lane == 0) {
    if (jmax < jmin) { jlo_a[row] = 0; cnt_a[row] = 0; }
    else             { jlo_a[row] = jmin; cnt_a[row] = jmax - jmin + 1; }
  }
}

// ---------------------------------------------------------------------------
// Kernel B: prefix sum over 4-padded row counts; per-row meta
// int4(iq*NLON, jlo (signed), cnt4, pool offset).
// ---------------------------------------------------------------------------
__global__ __launch_bounds__(256) void scan_kernel(
    const int* __restrict__ cnt_a, const int* __restrict__ jlo_a,
    int* __restrict__ off_a, int4* __restrict__ rowmeta, int tap_cap)
{
  __shared__ int buf[256];
  __shared__ int carry;
  int tid = threadIdx.x;
  if (tid == 0) carry = 0;
  __syncthreads();
  for (int base = 0; base < NROWS; base += 256) {
    int i = base + tid;
    int v = (i < NROWS) ? ((cnt_a[i] + 3) & ~3) : 0;
    buf[tid] = v;
    __syncthreads();
    for (int s = 1; s < 256; s <<= 1) {
      int t = (tid >= s) ? buf[tid - s] : 0;
      __syncthreads();
      buf[tid] += t;
      __syncthreads();
    }
    if (i < NROWS) off_a[i] = carry + buf[tid] - v;   // exclusive
    __syncthreads();
    if (tid == 255) carry += buf[255];
    __syncthreads();
  }
  __syncthreads();
  for (int r = tid; r < NROWS; r += 256) {
    int off = off_a[r];
    int c4  = (cnt_a[r] + 3) & ~3;
    if (off >= tap_cap)           c4 = 0;
    else if (off + c4 > tap_cap)  c4 = (tap_cap - off) & ~3;
    int l = r / ND, d = r - ND * l;
    int iq = min(max(l + d - 2, 0), NLAT - 1);
    rowmeta[r] = make_int4(iq * NLON, jlo_a[r], c4, off);
  }
}

// ---------------------------------------------------------------------------
// Kernel C: fill weight pool (Kg_c, Kg_s, Kd_c, Kd_s), zero-padded to x4.
// ---------------------------------------------------------------------------
__global__ __launch_bounds__(64) void fill_kernel(
    const float* __restrict__ Kgc, const float* __restrict__ Kgs,
    const float* __restrict__ Kdc, const float* __restrict__ Kds,
    const int* __restrict__ jlo_a, const int* __restrict__ cnt_a,
    const int* __restrict__ off_a,
    float4* __restrict__ tapw, int tap_cap)
{
  int row = blockIdx.x;
  int jlo = jlo_a[row], cnt = cnt_a[row], off = off_a[row];
  int cnt4 = (cnt + 3) & ~3;
  for (int t = threadIdx.x; t < cnt4; t += 64) {
    int p = off + t;
    if (p >= tap_cap) break;
    float4 w = make_float4(0.f, 0.f, 0.f, 0.f);
    if (t < cnt) {
      int j = jlo + t;
      int m = j + ((j < 0) ? NLON : 0);
      size_t idx = (size_t)row * NLON + m;
      w = make_float4(Kgc[idx], Kgs[idx], Kdc[idx], Kds[idx]);
    }
    tapw[p] = w;
  }
}

// ---------------------------------------------------------------------------
// Shared epilogue: Coriolis + RK4 combine for 4 consecutive columns at ih.
// mode 0: O = S0 + cdt*k ; mode 1: O = (X1+2*X2+X3-S0)/3 + (DT/6)*k4
// ---------------------------------------------------------------------------
__device__ __forceinline__ void rk4_epilogue(
    float ah0, float ah1, float ah2, float ah3,
    float au0, float au1, float au2, float au3,
    float av0, float av1, float av2, float av3,
    size_t ih, float f,
    const float* __restrict__ Xh,  const float* __restrict__ Xuv,
    const float* __restrict__ S0h, const float* __restrict__ S0uv,
    const float* __restrict__ X1h, const float* __restrict__ X1uv,
    const float* __restrict__ X2h, const float* __restrict__ X2uv,
    float* __restrict__ Oh, float* __restrict__ Ouv,
    float cdt, int mode)
{
  size_t iuv = 2 * ih;
  float4 xa = *(const float4*)(Xuv + iuv);      // u0,v0,u1,v1
  float4 xb = *(const float4*)(Xuv + iuv + 4);  // u2,v2,u3,v3
  float kh0 = -ah0, kh1 = -ah1, kh2 = -ah2, kh3 = -ah3;
  float ku0 = fmaf(-f, xa.y, -au0), kv0 = fmaf(f, xa.x, -av0);
  float ku1 = fmaf(-f, xa.w, -au1), kv1 = fmaf(f, xa.z, -av1);
  float ku2 = fmaf(-f, xb.y, -au2), kv2 = fmaf(f, xb.x, -av2);
  float ku3 = fmaf(-f, xb.w, -au3), kv3 = fmaf(f, xb.z, -av3);

  if (mode == 0) {
    float4 s0 = *(const float4*)(S0h + ih);
    *(float4*)(Oh + ih) = make_float4(fmaf(cdt, kh0, s0.x), fmaf(cdt, kh1, s0.y),
                                      fmaf(cdt, kh2, s0.z), fmaf(cdt, kh3, s0.w));
    float4 sa = *(const float4*)(S0uv + iuv);
    float4 sb = *(const float4*)(S0uv + iuv + 4);
    *(float4*)(Ouv + iuv)     = make_float4(fmaf(cdt, ku0, sa.x), fmaf(cdt, kv0, sa.y),
                                            fmaf(cdt, ku1, sa.z), fmaf(cdt, kv1, sa.w));
    *(float4*)(Ouv + iuv + 4) = make_float4(fmaf(cdt, ku2, sb.x), fmaf(cdt, kv2, sb.y),
                                            fmaf(cdt, ku3, sb.z), fmaf(cdt, kv3, sb.w));
  } else {
    const float DT6 = DTSTEP / 6.0f;
    const float TH  = 1.0f / 3.0f;
    float4 xh3 = *(const float4*)(Xh + ih);   // X3 h at own cols
    float4 s0 = *(const float4*)(S0h + ih);
    float4 x1 = *(const float4*)(X1h + ih);
    float4 x2 = *(const float4*)(X2h + ih);
    *(float4*)(Oh + ih) = make_float4(
      TH * (x1.x + 2.f * x2.x + xh3.x - s0.x) + DT6 * kh0,
      TH * (x1.y + 2.f * x2.y + xh3.y - s0.y) + DT6 * kh1,
      TH * (x1.z + 2.f * x2.z + xh3.z - s0.z) + DT6 * kh2,
      TH * (x1.w + 2.f * x2.w + xh3.w - s0.w) + DT6 * kh3);
    float4 sa = *(const float4*)(S0uv + iuv);
    float4 sb = *(const float4*)(S0uv + iuv + 4);
    float4 xa1 = *(const float4*)(X1uv + iuv);
    float4 xb1 = *(const float4*)(X1uv + iuv + 4);
    float4 xa2 = *(const float4*)(X2uv + iuv);
    float4 xb2 = *(const float4*)(X2uv + iuv + 4);
    *(float4*)(Ouv + iuv) = make_float4(
      TH * (xa1.x + 2.f * xa2.x + xa.x - sa.x) + DT6 * ku0,
      TH * (xa1.y + 2.f * xa2.y + xa.y - sa.y) + DT6 * kv0,
      TH * (xa1.z + 2.f * xa2.z + xa.z - sa.z) + DT6 * ku1,
      TH * (xa1.w + 2.f * xa2.w + xa.w - sa.w) + DT6 * kv1);
    *(float4*)(Ouv + iuv + 4) = make_float4(
      TH * (xb1.x + 2.f * xb2.x + xb.x - sb.x) + DT6 * ku2,
      TH * (xb1.y + 2.f * xb2.y + xb.y - sb.y) + DT6 * kv2,
      TH * (xb1.z + 2.f * xb2.z + xb.z - sb.z) + DT6 * ku3,
      TH * (xb1.w + 2.f * xb2.w + xb.w - sb.w) + DT6 * kv3);
  }
}

// 16B-block XOR swizzle: spreads stride-32B b128 reads over 8 distinct
// 16B slots (preserves float4 contiguity: only bits [4:2] are XORed with
// bits [8:6], identical within any aligned 4-dword block).
__device__ __forceinline__ int swz(int d) { return d ^ ((d >> 4) & 28); }

__device__ __forceinline__ float4 ldswz(const float* base, int o) {
  return *(const float4*)(base + swz(o));
}

__device__ __forceinline__ float getc(const float4& v, int k) {
  switch (k & 3) { case 0: return v.x; case 1: return v.y; case 2: return v.z; default: return v.w; }
}

// ---------------------------------------------------------------------------
// Stage kernel.  Grid 3*NLAT*NB (3 col-blocks of 512 cols, overlap at the
// seam).  Block 512 = 8 independent wave-teams; per lat the (row d, 64-tap
// chunk) items are strided across teams (item = team; item += 8) with NO
// barriers in the loop (private LDS slice per team, wave-internal fences).
// Lane owns 8 cols: rolling 12-float window per field (3 x ldswz b128/group),
// weights read from global via readfirstlane-uniform address (scalar path).
// Final: one __syncthreads, teams 1..7 dump partials, team 0 combines +
// Coriolis/RK4 epilogue.
// ---------------------------------------------------------------------------
__global__ __launch_bounds__(BTK, 4) void stage_kernel(
    const float* __restrict__ Xh,  const float* __restrict__ Xuv,
    const float* __restrict__ S0h, const float* __restrict__ S0uv,
    const float* __restrict__ X1h, const float* __restrict__ X1uv,
    const float* __restrict__ X2h, const float* __restrict__ X2uv,
    const float* __restrict__ fcor,
    const int4* __restrict__ rowmeta, const float4* __restrict__ tapw,
    float* __restrict__ Oh, float* __restrict__ Ouv,
    float cdt, int mode)
{
  __shared__ __align__(16) float smem[NTK * TFK];

  int x  = blockIdx.x;
  int cb = x % 3;
  int r  = x / 3;
  int b  = r & 3;
  int ly = r >> 2;                                           // 0..720
  int l  = (ly & 1) ? (NLAT - 1 - (ly >> 1)) : (ly >> 1);    // heavy-first
  int c0 = (cb < 2) ? cb * NCK : (NLON - NCK);               // 0,512,928
  int tid  = threadIdx.x;
  int team = tid >> 6;
  int lane = tid & 63;

  float* __restrict__ sl = smem + team * TFK;
  float* __restrict__ sh = sl;
  float* __restrict__ su = sl + WLK;
  float* __restrict__ sv = sl + 2 * WLK;

  const float* __restrict__ xh  = Xh  + (size_t)b * PLANE;
  const float* __restrict__ xuv = Xuv + (size_t)b * PLANE * 2;

  // --- per-lat item partition: item -> (d row, 64-tap chunk) ---
  int4 rms[ND];
  int ns[ND + 1];
  ns[0] = 0;
#pragma unroll
  for (int d = 0; d < ND; ++d) {
    rms[d] = rowmeta[l * ND + d];
    ns[d + 1] = ns[d] + (rms[d].z + TCHK - 1) / TCHK;
  }
  int nit = ns[ND];

  float ah[8], au[8], av[8];
#pragma unroll
  for (int j = 0; j < 8; ++j) { ah[j] = 0.f; au[j] = 0.f; av[j] = 0.f; }

  int o0 = lane * 8;

  for (int item = team; item < nit; item += NTK) {
    int dd = 0;
#pragma unroll
    for (int d = 0; d < ND; ++d)
      if (item >= ns[d] && item < ns[d + 1]) dd = d;
    int4 rm = rms[dd];
    int tc = (item - ns[dd]) * TCHK;
    int wcnt = min(TCHK, rm.z - tc);          // multiple of 4, >= 4
    int wlen = NCK + wcnt;                    // stage indices 0 .. 511+wcnt
    int gg = c0 + rm.y + tc;
    gg %= NLON; if (gg < 0) gg += NLON;
    const float* __restrict__ grh  = xh  + rm.x;
    const float* __restrict__ gruv = xuv + 2 * (size_t)rm.x;

    for (int e = lane; e < wlen; e += 64) {
      int g = gg + e;                         // < 1440 + 576
      if (g >= NLON) g -= NLON;
      float  hh = grh[g];
      float2 uv = *(const float2*)(gruv + 2 * g);
      int se = swz(e);
      sh[se] = hh; su[se] = uv.x; sv[se] = uv.y;
    }
    // wave-internal: ensure ds_writes complete before cross-lane ds_reads
    asm volatile("s_waitcnt lgkmcnt(0)" ::: "memory");
    __builtin_amdgcn_sched_barrier(0);

    int wb = __builtin_amdgcn_readfirstlane(rm.w + tc);  // uniform -> SMEM loads

    float4 HA = ldswz(sh, o0),     HB = ldswz(sh, o0 + 4), HC = ldswz(sh, o0 + 8);
    float4 UA = ldswz(su, o0),     UB = ldswz(su, o0 + 4), UC = ldswz(su, o0 + 8);
    float4 VA = ldswz(sv, o0),     VB = ldswz(sv, o0 + 4), VC = ldswz(sv, o0 + 8);

    for (int tg = 0; tg < wcnt; tg += 4) {
#pragma unroll
      for (int i = 0; i < 4; ++i) {
        float4 W = tapw[wb + tg + i];
#pragma unroll
        for (int j = 0; j < 8; ++j) {
          const int k = i + j;
          float hx = (k < 4) ? getc(HA, k) : (k < 8) ? getc(HB, k - 4) : getc(HC, k - 8);
          float ux = (k < 4) ? getc(UA, k) : (k < 8) ? getc(UB, k - 4) : getc(UC, k - 8);
          float vx = (k < 4) ? getc(VA, k) : (k < 8) ? getc(VB, k - 4) : getc(VC, k - 8);
          ah[j] = fmaf(W.z, ux, ah[j]);
          ah[j] = fmaf(W.w, vx, ah[j]);
          au[j] = fmaf(W.x, hx, au[j]);
          av[j] = fmaf(W.y, hx, av[j]);
        }
      }
      HA = HB; HB = HC; HC = ldswz(sh, o0 + tg + 12);
      UA = UB; UB = UC; UC = ldswz(su, o0 + tg + 12);
      VA = VB; VB = VC; VC = ldswz(sv, o0 + tg + 12);
    }
  }

  // ---- cross-team combine (single barrier) ----
  if (team != 0) {
    float* cs = sl + lane * 24;
    *(float4*)(cs +  0) = make_float4(ah[0], ah[1], ah[2], ah[3]);
    *(float4*)(cs +  4) = make_float4(ah[4], ah[5], ah[6], ah[7]);
    *(float4*)(cs +  8) = make_float4(au[0], au[1], au[2], au[3]);
    *(float4*)(cs + 12) = make_float4(au[4], au[5], au[6], au[7]);
    *(float4*)(cs + 16) = make_float4(av[0], av[1], av[2], av[3]);
    *(float4*)(cs + 20) = make_float4(av[4], av[5], av[6], av[7]);
  }
  __syncthreads();

  if (team == 0) {
#pragma unroll
    for (int t = 1; t < NTK; ++t) {
      const float* cs = smem + t * TFK + lane * 24;
      float4 a0 = *(const float4*)(cs +  0);
      float4 a1 = *(const float4*)(cs +  4);
      float4 b0 = *(const float4*)(cs +  8);
      float4 b1 = *(const float4*)(cs + 12);
      float4 d0 = *(const float4*)(cs + 16);
      float4 d1 = *(const float4*)(cs + 20);
      ah[0] += a0.x; ah[1] += a0.y; ah[2] += a0.z; ah[3] += a0.w;
      ah[4] += a1.x; ah[5] += a1.y; ah[6] += a1.z; ah[7] += a1.w;
      au[0] += b0.x; au[1] += b0.y; au[2] += b0.z; au[3] += b0.w;
      au[4] += b1.x; au[5] += b1.y; au[6] += b1.z; au[7] += b1.w;
      av[0] += d0.x; av[1] += d0.y; av[2] += d0.z; av[3] += d0.w;
      av[4] += d1.x; av[5] += d1.y; av[6] += d1.z; av[7] += d1.w;
    }
    float f = fcor[l];
    size_t ih = (size_t)b * PLANE + (size_t)l * NLON + c0 + o0;
    rk4_epilogue(ah[0], ah[1], ah[2], ah[3], au[0], au[1], au[2], au[3],
                 av[0], av[1], av[2], av[3], ih, f,
                 Xh, Xuv, S0h, S0uv, X1h, X1uv, X2h, X2uv, Oh, Ouv, cdt, mode);
    rk4_epilogue(ah[4], ah[5], ah[6], ah[7], au[4], au[5], au[6], au[7],
                 av[4], av[5], av[6], av[7], ih + 4, f,
                 Xh, Xuv, S0h, S0uv, X1h, X1uv, X2h, X2uv, Oh, Ouv, cdt, mode);
  }
}

// ---------------------------------------------------------------------------
extern "C" void kernel_launch(void* const* d_in, const int* in_sizes, int n_in,
                              void* d_out, int out_size, void* d_ws, size_t ws_size,
                              hipStream_t stream)
{
  const float* h0   = (const float*)d_in[0];
  const float* uv0  = (const float*)d_in[1];
  const float* Kgc  = (const float*)d_in[2];
  const float* Kgs  = (const float*)d_in[3];
  const float* Kdc  = (const float*)d_in[4];
  const float* Kds  = (const float*)d_in[5];
  const float* fcor = (const float*)d_in[6];

  char* ws = (char*)d_ws;
  size_t pos = 0;
  auto carve = [&](size_t bytes) -> void* {
    void* p = ws + pos;
    pos += (bytes + 255) & ~(size_t)255;
    return p;
  };

  int*   jlo_a   = (int*)carve(sizeof(int) * NROWS);
  int*   cnt_a   = (int*)carve(sizeof(int) * NROWS);
  int*   off_a   = (int*)carve(sizeof(int) * NROWS);
  int4*  rowmeta = (int4*)carve(sizeof(int4) * NROWS);
  float* X1      = (float*)carve(sizeof(float) * 3 * (size_t)HVOL);
  float* X2      = (float*)carve(sizeof(float) * 3 * (size_t)HVOL);
  float* X3      = (float*)carve(sizeof(float) * 3 * (size_t)HVOL);
  float4* tapw   = (float4*)carve(sizeof(float4) * (size_t)TAPCAP);

  float* X1h = X1;  float* X1uv = X1 + HVOL;
  float* X2h = X2;  float* X2uv = X2 + HVOL;
  float* X3h = X3;  float* X3uv = X3 + HVOL;
  float* out_h  = (float*)d_out;          // [NB,1,NLAT,NLON]
  float* out_uv = (float*)d_out + HVOL;   // [NB,1,NLAT,NLON,2]

  support_kernel<<<NROWS, 64, 0, stream>>>(Kgc, Kgs, Kdc, Kds, jlo_a, cnt_a);
  scan_kernel<<<1, 256, 0, stream>>>(cnt_a, jlo_a, off_a, rowmeta, TAPCAP);
  fill_kernel<<<NROWS, 64, 0, stream>>>(Kgc, Kgs, Kdc, Kds, jlo_a, cnt_a, off_a,
                                        tapw, TAPCAP);

  dim3 gs(3 * NLAT * NB);

  // stage 1: k1 from S0; X1 = S0 + dt/2 k1
  stage_kernel<<<gs, BTK, 0, stream>>>(h0, uv0, h0, uv0, h0, uv0, h0, uv0, fcor,
                                       rowmeta, tapw, X1h, X1uv, 0.5f * DTSTEP, 0);
  // stage 2: k2 from X1; X2 = S0 + dt/2 k2
  stage_kernel<<<gs, BTK, 0, stream>>>(X1h, X1uv, h0, uv0, h0, uv0, h0, uv0, fcor,
                                       rowmeta, tapw, X2h, X2uv, 0.5f * DTSTEP, 0);
  // stage 3: k3 from X2; X3 = S0 + dt k3
  stage_kernel<<<gs, BTK, 0, stream>>>(X2h, X2uv, h0, uv0, h0, uv0, h0, uv0, fcor,
                                       rowmeta, tapw, X3h, X3uv, DTSTEP, 0);
  // stage 4: k4 from X3; out = (X1 + 2 X2 + X3 - S0)/3 + dt/6 k4
  stage_kernel<<<gs, BTK, 0, stream>>>(X3h, X3uv, h0, uv0, X1h, X1uv, X2h, X2uv, fcor,
                                       rowmeta, tapw, out_h, out_uv, 0.0f, 1);
}

// Round 5
// 851.230 us; speedup vs baseline: 1.3694x; 1.2494x over previous
//
#include <hip/hip_runtime.h>

#define NLAT 721
#define NLON 1440
#define NB 4
#define ND 5
#define NROWS (NLAT*ND)          // 3605
#define PLANE (NLAT*NLON)        // 1,038,240
#define HVOL (NB*PLANE)          // 4,152,960
#define DTSTEP 0.01f
#define TAPCAP 262144

// ---- stage kernel geometry ----
#define NCK 512                  // cols per block (lane owns 8)
#define TCHK 64                  // taps per team-chunk (multiple of 4)
#define NTK 8                    // wave-teams per block
#define BTK (NTK*64)             // 512 threads
#define WLK 608                  // per-field slice floats (512+64+4 + swizzle pad)
#define TFK (3*WLK)              // team slice floats (1824 -> 7296 B; x8 = 58 KB)

// ---------------------------------------------------------------------------
// Kernel A: per (lat,d) row, find the wrapped-interval support [jlo, jhi]
// ---------------------------------------------------------------------------
__global__ __launch_bounds__(64) void support_kernel(
    const float* __restrict__ Kgc, const float* __restrict__ Kgs,
    const float* __restrict__ Kdc, const float* __restrict__ Kds,
    int* __restrict__ jlo_a, int* __restrict__ cnt_a)
{
  int row = blockIdx.x;
  int lane = threadIdx.x;
  const float* a = Kgc + (size_t)row * NLON;
  const float* b = Kgs + (size_t)row * NLON;
  const float* c = Kdc + (size_t)row * NLON;
  const float* d = Kds + (size_t)row * NLON;
  int jmin = 1 << 30, jmax = -(1 << 30);
  for (int m = lane; m < NLON; m += 64) {
    float s = fabsf(a[m]) + fabsf(b[m]) + fabsf(c[m]) + fabsf(d[m]);
    if (s != 0.0f) {
      int j = (m >= NLON / 2) ? (m - NLON) : m;
      jmin = min(jmin, j);
      jmax = max(jmax, j);
    }
  }
  for (int s = 32; s > 0; s >>= 1) {
    jmin = min(jmin, __shfl_down(jmin, s));
    jmax = max(jmax, __shfl_down(jmax, s));
  }
  if (lane == 0) {
    if (jmax < jmin) { jlo_a[row] = 0; cnt_a[row] = 0; }
    else             { jlo_a[row] = jmin; cnt_a[row] = jmax - jmin + 1; }
  }
}

// ---------------------------------------------------------------------------
// Kernel B: prefix sum over 4-padded row counts; per-row meta
// int4(iq*NLON, jlo (signed), cnt4, pool offset).
// ---------------------------------------------------------------------------
__global__ __launch_bounds__(256) void scan_kernel(
    const int* __restrict__ cnt_a, const int* __restrict__ jlo_a,
    int* __restrict__ off_a, int4* __restrict__ rowmeta, int tap_cap)
{
  __shared__ int buf[256];
  __shared__ int carry;
  int tid = threadIdx.x;
  if (tid == 0) carry = 0;
  __syncthreads();
  for (int base = 0; base < NROWS; base += 256) {
    int i = base + tid;
    int v = (i < NROWS) ? ((cnt_a[i] + 3) & ~3) : 0;
    buf[tid] = v;
    __syncthreads();
    for (int s = 1; s < 256; s <<= 1) {
      int t = (tid >= s) ? buf[tid - s] : 0;
      __syncthreads();
      buf[tid] += t;
      __syncthreads();
    }
    if (i < NROWS) off_a[i] = carry + buf[tid] - v;   // exclusive
    __syncthreads();
    if (tid == 255) carry += buf[255];
    __syncthreads();
  }
  __syncthreads();
  for (int r = tid; r < NROWS; r += 256) {
    int off = off_a[r];
    int c4  = (cnt_a[r] + 3) & ~3;
    if (off >= tap_cap)           c4 = 0;
    else if (off + c4 > tap_cap)  c4 = (tap_cap - off) & ~3;
    int l = r / ND, d = r - ND * l;
    int iq = min(max(l + d - 2, 0), NLAT - 1);
    rowmeta[r] = make_int4(iq * NLON, jlo_a[r], c4, off);
  }
}

// ---------------------------------------------------------------------------
// Kernel C: fill weight pool (Kg_c, Kg_s, Kd_c, Kd_s), zero-padded to x4.
// ---------------------------------------------------------------------------
__global__ __launch_bounds__(64) void fill_kernel(
    const float* __restrict__ Kgc, const float* __restrict__ Kgs,
    const float* __restrict__ Kdc, const float* __restrict__ Kds,
    const int* __restrict__ jlo_a, const int* __restrict__ cnt_a,
    const int* __restrict__ off_a,
    float4* __restrict__ tapw, int tap_cap)
{
  int row = blockIdx.x;
  int jlo = jlo_a[row], cnt = cnt_a[row], off = off_a[row];
  int cnt4 = (cnt + 3) & ~3;
  for (int t = threadIdx.x; t < cnt4; t += 64) {
    int p = off + t;
    if (p >= tap_cap) break;
    float4 w = make_float4(0.f, 0.f, 0.f, 0.f);
    if (t < cnt) {
      int j = jlo + t;
      int m = j + ((j < 0) ? NLON : 0);
      size_t idx = (size_t)row * NLON + m;
      w = make_float4(Kgc[idx], Kgs[idx], Kdc[idx], Kds[idx]);
    }
    tapw[p] = w;
  }
}

// ---------------------------------------------------------------------------
// Shared epilogue: Coriolis + RK4 combine for 4 consecutive columns at ih.
// mode 0: O = S0 + cdt*k ; mode 1: O = (X1+2*X2+X3-S0)/3 + (DT/6)*k4
// ---------------------------------------------------------------------------
__device__ __forceinline__ void rk4_epilogue(
    float ah0, float ah1, float ah2, float ah3,
    float au0, float au1, float au2, float au3,
    float av0, float av1, float av2, float av3,
    size_t ih, float f,
    const float* __restrict__ Xh,  const float* __restrict__ Xuv,
    const float* __restrict__ S0h, const float* __restrict__ S0uv,
    const float* __restrict__ X1h, const float* __restrict__ X1uv,
    const float* __restrict__ X2h, const float* __restrict__ X2uv,
    float* __restrict__ Oh, float* __restrict__ Ouv,
    float cdt, int mode)
{
  size_t iuv = 2 * ih;
  float4 xa = *(const float4*)(Xuv + iuv);      // u0,v0,u1,v1
  float4 xb = *(const float4*)(Xuv + iuv + 4);  // u2,v2,u3,v3
  float kh0 = -ah0, kh1 = -ah1, kh2 = -ah2, kh3 = -ah3;
  float ku0 = fmaf(-f, xa.y, -au0), kv0 = fmaf(f, xa.x, -av0);
  float ku1 = fmaf(-f, xa.w, -au1), kv1 = fmaf(f, xa.z, -av1);
  float ku2 = fmaf(-f, xb.y, -au2), kv2 = fmaf(f, xb.x, -av2);
  float ku3 = fmaf(-f, xb.w, -au3), kv3 = fmaf(f, xb.z, -av3);

  if (mode == 0) {
    float4 s0 = *(const float4*)(S0h + ih);
    *(float4*)(Oh + ih) = make_float4(fmaf(cdt, kh0, s0.x), fmaf(cdt, kh1, s0.y),
                                      fmaf(cdt, kh2, s0.z), fmaf(cdt, kh3, s0.w));
    float4 sa = *(const float4*)(S0uv + iuv);
    float4 sb = *(const float4*)(S0uv + iuv + 4);
    *(float4*)(Ouv + iuv)     = make_float4(fmaf(cdt, ku0, sa.x), fmaf(cdt, kv0, sa.y),
                                            fmaf(cdt, ku1, sa.z), fmaf(cdt, kv1, sa.w));
    *(float4*)(Ouv + iuv + 4) = make_float4(fmaf(cdt, ku2, sb.x), fmaf(cdt, kv2, sb.y),
                                            fmaf(cdt, ku3, sb.z), fmaf(cdt, kv3, sb.w));
  } else {
    const float DT6 = DTSTEP / 6.0f;
    const float TH  = 1.0f / 3.0f;
    float4 xh3 = *(const float4*)(Xh + ih);   // X3 h at own cols
    float4 s0 = *(const float4*)(S0h + ih);
    float4 x1 = *(const float4*)(X1h + ih);
    float4 x2 = *(const float4*)(X2h + ih);
    *(float4*)(Oh + ih) = make_float4(
      TH * (x1.x + 2.f * x2.x + xh3.x - s0.x) + DT6 * kh0,
      TH * (x1.y + 2.f * x2.y + xh3.y - s0.y) + DT6 * kh1,
      TH * (x1.z + 2.f * x2.z + xh3.z - s0.z) + DT6 * kh2,
      TH * (x1.w + 2.f * x2.w + xh3.w - s0.w) + DT6 * kh3);
    float4 sa = *(const float4*)(S0uv + iuv);
    float4 sb = *(const float4*)(S0uv + iuv + 4);
    float4 xa1 = *(const float4*)(X1uv + iuv);
    float4 xb1 = *(const float4*)(X1uv + iuv + 4);
    float4 xa2 = *(const float4*)(X2uv + iuv);
    float4 xb2 = *(const float4*)(X2uv + iuv + 4);
    *(float4*)(Ouv + iuv) = make_float4(
      TH * (xa1.x + 2.f * xa2.x + xa.x - sa.x) + DT6 * ku0,
      TH * (xa1.y + 2.f * xa2.y + xa.y - sa.y) + DT6 * kv0,
      TH * (xa1.z + 2.f * xa2.z + xa.z - sa.z) + DT6 * ku1,
      TH * (xa1.w + 2.f * xa2.w + xa.w - sa.w) + DT6 * kv1);
    *(float4*)(Ouv + iuv + 4) = make_float4(
      TH * (xb1.x + 2.f * xb2.x + xb.x - sb.x) + DT6 * ku2,
      TH * (xb1.y + 2.f * xb2.y + xb.y - sb.y) + DT6 * kv2,
      TH * (xb1.z + 2.f * xb2.z + xb.z - sb.z) + DT6 * ku3,
      TH * (xb1.w + 2.f * xb2.w + xb.w - sb.w) + DT6 * kv3);
  }
}

// 16B-block XOR swizzle: spreads stride-32B b128 reads over 8 distinct
// 16B slots (preserves float4 contiguity: only bits [4:2] are XORed with
// bits [8:6], identical within any aligned 4-dword block).
__device__ __forceinline__ int swz(int d) { return d ^ ((d >> 4) & 28); }

__device__ __forceinline__ float4 ldswz(const float* base, int o) {
  return *(const float4*)(base + swz(o));
}

__device__ __forceinline__ float getc(const float4& v, int k) {
  switch (k & 3) { case 0: return v.x; case 1: return v.y; case 2: return v.z; default: return v.w; }
}

// ---------------------------------------------------------------------------
// Stage kernel.  Grid 3*NLAT*NB (3 col-blocks of 512 cols, overlap at the
// seam).  Block 512 = 8 independent wave-teams; per lat the (row d, 64-tap
// chunk) items are strided across teams (item = team; item += 8) with NO
// barriers in the loop (private LDS slice per team, wave-internal fences).
// Lane owns 8 cols: rolling 12-float window per field (3 x ldswz b128/group),
// weights read from global via readfirstlane-uniform address (scalar path).
// Item meta selected via UNROLLED CONSTANT-INDEX loop (no runtime array
// indexing -> no scratch; round-4's rms[dd] cost 425 MB/dispatch of scratch
// write-backs).  Final: one __syncthreads, teams 1..7 dump partials, team 0
// combines + Coriolis/RK4 epilogue.
// ---------------------------------------------------------------------------
__global__ __launch_bounds__(BTK, 4) void stage_kernel(
    const float* __restrict__ Xh,  const float* __restrict__ Xuv,
    const float* __restrict__ S0h, const float* __restrict__ S0uv,
    const float* __restrict__ X1h, const float* __restrict__ X1uv,
    const float* __restrict__ X2h, const float* __restrict__ X2uv,
    const float* __restrict__ fcor,
    const int4* __restrict__ rowmeta, const float4* __restrict__ tapw,
    float* __restrict__ Oh, float* __restrict__ Ouv,
    float cdt, int mode)
{
  __shared__ __align__(16) float smem[NTK * TFK];

  int x  = blockIdx.x;
  int cb = x % 3;
  int r  = x / 3;
  int b  = r & 3;
  int ly = r >> 2;                                           // 0..720
  int l  = (ly & 1) ? (NLAT - 1 - (ly >> 1)) : (ly >> 1);    // heavy-first
  int c0 = (cb < 2) ? cb * NCK : (NLON - NCK);               // 0,512,928
  int tid  = threadIdx.x;
  int team = tid >> 6;
  int lane = tid & 63;

  float* __restrict__ sl = smem + team * TFK;
  float* __restrict__ sh = sl;
  float* __restrict__ su = sl + WLK;
  float* __restrict__ sv = sl + 2 * WLK;

  const float* __restrict__ xh  = Xh  + (size_t)b * PLANE;
  const float* __restrict__ xuv = Xuv + (size_t)b * PLANE * 2;

  // --- per-lat item partition: item -> (d row, 64-tap chunk) ---
  // All arrays ONLY indexed with compile-time-constant d (registerized).
  int4 rms[ND];
  int ns[ND + 1];
  ns[0] = 0;
#pragma unroll
  for (int d = 0; d < ND; ++d) {
    rms[d] = rowmeta[l * ND + d];
    ns[d + 1] = ns[d] + (rms[d].z + TCHK - 1) / TCHK;
  }
  int nit = ns[ND];

  float ah[8], au[8], av[8];
#pragma unroll
  for (int j = 0; j < 8; ++j) { ah[j] = 0.f; au[j] = 0.f; av[j] = 0.f; }

  int o0 = lane * 8;

  for (int item = team; item < nit; item += NTK) {
    int4 rm = make_int4(0, 0, 0, 0);
    int tc = 0;
#pragma unroll
    for (int d = 0; d < ND; ++d)
      if (item >= ns[d] && item < ns[d + 1]) { rm = rms[d]; tc = (item - ns[d]) * TCHK; }

    int wcnt = min(TCHK, rm.z - tc);          // multiple of 4, >= 4
    int wlen = NCK + wcnt;                    // stage indices 0 .. 511+wcnt
    int gg = c0 + rm.y + tc;
    gg %= NLON; if (gg < 0) gg += NLON;
    const float* __restrict__ grh  = xh  + rm.x;
    const float* __restrict__ gruv = xuv + 2 * (size_t)rm.x;

    for (int e = lane; e < wlen; e += 64) {
      int g = gg + e;                         // < 1440 + 576
      if (g >= NLON) g -= NLON;
      float  hh = grh[g];
      float2 uv = *(const float2*)(gruv + 2 * g);
      int se = swz(e);
      sh[se] = hh; su[se] = uv.x; sv[se] = uv.y;
    }
    // wave-internal: ensure ds_writes complete before cross-lane ds_reads
    asm volatile("s_waitcnt lgkmcnt(0)" ::: "memory");
    __builtin_amdgcn_sched_barrier(0);

    int wb = __builtin_amdgcn_readfirstlane(rm.w + tc);  // uniform -> SMEM loads

    float4 HA = ldswz(sh, o0),     HB = ldswz(sh, o0 + 4), HC = ldswz(sh, o0 + 8);
    float4 UA = ldswz(su, o0),     UB = ldswz(su, o0 + 4), UC = ldswz(su, o0 + 8);
    float4 VA = ldswz(sv, o0),     VB = ldswz(sv, o0 + 4), VC = ldswz(sv, o0 + 8);

    for (int tg = 0; tg < wcnt; tg += 4) {
#pragma unroll
      for (int i = 0; i < 4; ++i) {
        float4 W = tapw[wb + tg + i];
#pragma unroll
        for (int j = 0; j < 8; ++j) {
          const int k = i + j;
          float hx = (k < 4) ? getc(HA, k) : (k < 8) ? getc(HB, k - 4) : getc(HC, k - 8);
          float ux = (k < 4) ? getc(UA, k) : (k < 8) ? getc(UB, k - 4) : getc(UC, k - 8);
          float vx = (k < 4) ? getc(VA, k) : (k < 8) ? getc(VB, k - 4) : getc(VC, k - 8);
          ah[j] = fmaf(W.z, ux, ah[j]);
          ah[j] = fmaf(W.w, vx, ah[j]);
          au[j] = fmaf(W.x, hx, au[j]);
          av[j] = fmaf(W.y, hx, av[j]);
        }
      }
      HA = HB; HB = HC; HC = ldswz(sh, o0 + tg + 12);
      UA = UB; UB = UC; UC = ldswz(su, o0 + tg + 12);
      VA = VB; VB = VC; VC = ldswz(sv, o0 + tg + 12);
    }
  }

  // ---- cross-team combine (single barrier) ----
  if (team != 0) {
    float* cs = sl + lane * 24;
    *(float4*)(cs +  0) = make_float4(ah[0], ah[1], ah[2], ah[3]);
    *(float4*)(cs +  4) = make_float4(ah[4], ah[5], ah[6], ah[7]);
    *(float4*)(cs +  8) = make_float4(au[0], au[1], au[2], au[3]);
    *(float4*)(cs + 12) = make_float4(au[4], au[5], au[6], au[7]);
    *(float4*)(cs + 16) = make_float4(av[0], av[1], av[2], av[3]);
    *(float4*)(cs + 20) = make_float4(av[4], av[5], av[6], av[7]);
  }
  __syncthreads();

  if (team == 0) {
#pragma unroll
    for (int t = 1; t < NTK; ++t) {
      const float* cs = smem + t * TFK + lane * 24;
      float4 a0 = *(const float4*)(cs +  0);
      float4 a1 = *(const float4*)(cs +  4);
      float4 b0 = *(const float4*)(cs +  8);
      float4 b1 = *(const float4*)(cs + 12);
      float4 d0 = *(const float4*)(cs + 16);
      float4 d1 = *(const float4*)(cs + 20);
      ah[0] += a0.x; ah[1] += a0.y; ah[2] += a0.z; ah[3] += a0.w;
      ah[4] += a1.x; ah[5] += a1.y; ah[6] += a1.z; ah[7] += a1.w;
      au[0] += b0.x; au[1] += b0.y; au[2] += b0.z; au[3] += b0.w;
      au[4] += b1.x; au[5] += b1.y; au[6] += b1.z; au[7] += b1.w;
      av[0] += d0.x; av[1] += d0.y; av[2] += d0.z; av[3] += d0.w;
      av[4] += d1.x; av[5] += d1.y; av[6] += d1.z; av[7] += d1.w;
    }
    float f = fcor[l];
    size_t ih = (size_t)b * PLANE + (size_t)l * NLON + c0 + o0;
    rk4_epilogue(ah[0], ah[1], ah[2], ah[3], au[0], au[1], au[2], au[3],
                 av[0], av[1], av[2], av[3], ih, f,
                 Xh, Xuv, S0h, S0uv, X1h, X1uv, X2h, X2uv, Oh, Ouv, cdt, mode);
    rk4_epilogue(ah[4], ah[5], ah[6], ah[7], au[4], au[5], au[6], au[7],
                 av[4], av[5], av[6], av[7], ih + 4, f,
                 Xh, Xuv, S0h, S0uv, X1h, X1uv, X2h, X2uv, Oh, Ouv, cdt, mode);
  }
}

// ---------------------------------------------------------------------------
extern "C" void kernel_launch(void* const* d_in, const int* in_sizes, int n_in,
                              void* d_out, int out_size, void* d_ws, size_t ws_size,
                              hipStream_t stream)
{
  const float* h0   = (const float*)d_in[0];
  const float* uv0  = (const float*)d_in[1];
  const float* Kgc  = (const float*)d_in[2];
  const float* Kgs  = (const float*)d_in[3];
  const float* Kdc  = (const float*)d_in[4];
  const float* Kds  = (const float*)d_in[5];
  const float* fcor = (const float*)d_in[6];

  char* ws = (char*)d_ws;
  size_t pos = 0;
  auto carve = [&](size_t bytes) -> void* {
    void* p = ws + pos;
    pos += (bytes + 255) & ~(size_t)255;
    return p;
  };

  int*   jlo_a   = (int*)carve(sizeof(int) * NROWS);
  int*   cnt_a   = (int*)carve(sizeof(int) * NROWS);
  int*   off_a   = (int*)carve(sizeof(int) * NROWS);
  int4*  rowmeta = (int4*)carve(sizeof(int4) * NROWS);
  float* X1      = (float*)carve(sizeof(float) * 3 * (size_t)HVOL);
  float* X2      = (float*)carve(sizeof(float) * 3 * (size_t)HVOL);
  float* X3      = (float*)carve(sizeof(float) * 3 * (size_t)HVOL);
  float4* tapw   = (float4*)carve(sizeof(float4) * (size_t)TAPCAP);

  float* X1h = X1;  float* X1uv = X1 + HVOL;
  float* X2h = X2;  float* X2uv = X2 + HVOL;
  float* X3h = X3;  float* X3uv = X3 + HVOL;
  float* out_h  = (float*)d_out;          // [NB,1,NLAT,NLON]
  float* out_uv = (float*)d_out + HVOL;   // [NB,1,NLAT,NLON,2]

  support_kernel<<<NROWS, 64, 0, stream>>>(Kgc, Kgs, Kdc, Kds, jlo_a, cnt_a);
  scan_kernel<<<1, 256, 0, stream>>>(cnt_a, jlo_a, off_a, rowmeta, TAPCAP);
  fill_kernel<<<NROWS, 64, 0, stream>>>(Kgc, Kgs, Kdc, Kds, jlo_a, cnt_a, off_a,
                                        tapw, TAPCAP);

  dim3 gs(3 * NLAT * NB);

  // stage 1: k1 from S0; X1 = S0 + dt/2 k1
  stage_kernel<<<gs, BTK, 0, stream>>>(h0, uv0, h0, uv0, h0, uv0, h0, uv0, fcor,
                                       rowmeta, tapw, X1h, X1uv, 0.5f * DTSTEP, 0);
  // stage 2: k2 from X1; X2 = S0 + dt/2 k2
  stage_kernel<<<gs, BTK, 0, stream>>>(X1h, X1uv, h0, uv0, h0, uv0, h0, uv0, fcor,
                                       rowmeta, tapw, X2h, X2uv, 0.5f * DTSTEP, 0);
  // stage 3: k3 from X2; X3 = S0 + dt k3
  stage_kernel<<<gs, BTK, 0, stream>>>(X2h, X2uv, h0, uv0, h0, uv0, h0, uv0, fcor,
                                       rowmeta, tapw, X3h, X3uv, DTSTEP, 0);
  // stage 4: k4 from X3; out = (X1 + 2 X2 + X3 - S0)/3 + dt/6 k4
  stage_kernel<<<gs, BTK, 0, stream>>>(X3h, X3uv, h0, uv0, X1h, X1uv, X2h, X2uv, fcor,
                                       rowmeta, tapw, out_h, out_uv, 0.0f, 1);
}